// Round 2
// baseline (174.852 us; speedup 1.0000x reference)
//
#include <hip/hip_runtime.h>
#include <hip/hip_bf16.h>
#include <stdint.h>

// Problem constants (fixed by reference file)
#define N_NODES 50000
#define KDEG    16
#define NFEAT   128
#define NTPL    16
#define MTPL    8

// Workspace layout (floats):
//   ws[0    .. 2047]  tmean[t*128 + f]
//   ws[2048 .. 2063]  tsq[t]
//   ws[2064 .. 2079]  mCt[t]
//   ws[2080 .. 2095]  mCt2[t]

__global__ void ltfwg_prep(const float* __restrict__ tmpl,   // [16][8][8] f32
                           const float* __restrict__ tfeat,  // [16][8][128] f32
                           float* __restrict__ ws) {
    const int t   = blockIdx.x;    // 16 blocks
    const int tid = threadIdx.x;   // 128 threads

    // tmean + tsq from templates_features
    float s = 0.f, ssq = 0.f;
    #pragma unroll
    for (int m = 0; m < MTPL; ++m) {
        float v = tfeat[t * (MTPL * NFEAT) + m * NFEAT + tid];
        s += v;
        ssq += v * v;
    }
    ws[t * NFEAT + tid] = s * 0.125f;   // mean over 8 rows

    __shared__ float red[128];
    red[tid] = ssq;
    __syncthreads();
    for (int o = 64; o > 0; o >>= 1) {
        if (tid < o) red[tid] += red[tid + o];
        __syncthreads();
    }
    if (tid == 0) ws[2048 + t] = red[0] * 0.125f;  // mean over rows of (sum over feats)

    // mCt / mCt2 from templates (64 entries, wave 0 only)
    if (tid < 64) {
        float v = tmpl[t * 64 + tid];
        float sv = v, sv2 = v * v;
        #pragma unroll
        for (int off = 32; off >= 1; off >>= 1) {
            sv  += __shfl_xor(sv, off);
            sv2 += __shfl_xor(sv2, off);
        }
        if (tid == 0) {
            ws[2064 + t] = sv  * (1.f / 64.f);
            ws[2080 + t] = sv2 * (1.f / 64.f);
        }
    }
}

__global__ __launch_bounds__(256, 4)
void ltfwg_main(const float* __restrict__ x,       // [N,128] f32
                const int* __restrict__ dst,       // [N,16] neighbor ids
                const float* __restrict__ ws,
                float* __restrict__ out) {         // [N,16] f32
    const int lane   = threadIdx.x & 63;
    const int wave   = (blockIdx.x * blockDim.x + threadIdx.x) >> 6;
    const int nwaves = (gridDim.x * blockDim.x) >> 6;

    // Per-wave template constants: lane handles feature cols {2*lane, 2*lane+1}
    float tm0[NTPL], tm1[NTPL];
    #pragma unroll
    for (int t = 0; t < NTPL; ++t) {
        float2 tv = ((const float2*)(ws + t * NFEAT))[lane];
        tm0[t] = tv.x;
        tm1[t] = tv.y;
    }
    const int tl = lane & 15;
    const float A  = 0.5f * (ws[2048 + tl] + ws[2080 + tl]);  // 0.5*(tsq + mCt2)
    const float Bc = 0.5f - ws[2064 + tl];                    // 0.5 - mCt

    for (int n = wave; n < N_NODES; n += nwaves) {
        // lanes 0..15 hold the node's 16 neighbor ids (lanes 16..63 duplicate)
        const int nbr = dst[n * KDEG + (lane & 15)];

        // ---- feature accumulation: row gather, 2 f32 per lane per neighbor
        float fs0 = 0.f, fs1 = 0.f, sqa = 0.f;
        #pragma unroll
        for (int a = 0; a < KDEG; ++a) {
            int nid = __shfl(nbr, a);  // wave-uniform
            float2 fv = ((const float2*)x)[nid * (NFEAT / 2) + lane];
            fs0 += fv.x;
            fs1 += fv.y;
            sqa += fv.x * fv.x;
            sqa += fv.y * fv.y;
        }
        float dotp[NTPL];
        #pragma unroll
        for (int t = 0; t < NTPL; ++t) dotp[t] = fs0 * tm0[t] + fs1 * tm1[t];

        // ---- structure term: lane covers (a = lane>>2, c-chunk = lane&3)
        int nida = __shfl(nbr, lane >> 2);
        const int4* np = (const int4*)(dst + nida * KDEG) + (lane & 3);
        int4 cv = *np;
        uint32_t m = 0;
        #pragma unroll
        for (int b = 0; b < KDEG; ++b) {
            int vb = __shfl(nbr, b);
            uint32_t hit = (uint32_t)((cv.x == vb) | (cv.y == vb) |
                                      (cv.z == vb) | (cv.w == vb));
            m |= hit << b;
        }
        // OR across the 4 lanes of the same row a
        m |= (uint32_t)__shfl_xor((int)m, 1);
        m |= (uint32_t)__shfl_xor((int)m, 2);
        float cnt = (float)__popc(m);  // each row counted 4x across its quad

        // ---- wave reductions (sq, cnt, dot[16])
        #pragma unroll
        for (int off = 32; off >= 1; off >>= 1) {
            sqa += __shfl_xor(sqa, off);
            cnt += __shfl_xor(cnt, off);
            #pragma unroll
            for (int t = 0; t < NTPL; ++t) dotp[t] += __shfl_xor(dotp[t], off);
        }

        // lane t picks dot[t] (static unrolled select)
        float dsel = dotp[0];
        #pragma unroll
        for (int t = 1; t < NTPL; ++t) dsel = (lane == t) ? dotp[t] : dsel;

        if (lane < NTPL) {
            // out = 0.5*(sq/16 + tsq - 2*dot/16) + 0.5*(mC + mCt2 - 2*mC*mCt)
            float mC = cnt * (1.0f / 1024.0f);  // /4 (quad dup) /256 (K*K)
            float val = 0.03125f * sqa - 0.0625f * dsel + A + mC * Bc;
            out[n * NTPL + lane] = val;
        }
    }
}

extern "C" void kernel_launch(void* const* d_in, const int* in_sizes, int n_in,
                              void* d_out, int out_size, void* d_ws, size_t ws_size,
                              hipStream_t stream) {
    const float* x     = (const float*)d_in[0];   // f32 [50000,128]
    const int*   edge  = (const int*)d_in[1];     // int32 [2, 800000]
    const float* tmpl  = (const float*)d_in[2];   // f32 [16,8,8]
    const float* tfeat = (const float*)d_in[3];   // f32 [16,8,128]
    float* ws  = (float*)d_ws;
    float* out = (float*)d_out;

    const int* dst = edge + (N_NODES * KDEG);  // second row of edge_index

    ltfwg_prep<<<NTPL, 128, 0, stream>>>(tmpl, tfeat, ws);
    ltfwg_main<<<1024, 256, 0, stream>>>(x, dst, ws, out);
}

// Round 3
// 142.810 us; speedup vs baseline: 1.2244x; 1.2244x over previous
//
#include <hip/hip_runtime.h>
#include <stdint.h>

// Problem constants (fixed by reference file)
#define N_NODES 50000
#define KDEG    16
#define NFEAT   128
#define NTPL    16
#define MTPL    8

// Workspace layout (floats):
//   [0    .. 2047]  tmean[t*128 + f]
//   [2048 .. 2063]  tsq[t]
//   [2064 .. 2079]  mCt[t]
//   [2080 .. 2095]  mCt2[t]
//   [2112 .. ]      z[n*16 + t] = 0.5*s2[n] - y[n][t],  y[n][t] = x[n]·tmean_t
#define TMEAN_OFF 0
#define TSQ_OFF   2048
#define MCT_OFF   2064
#define MCT2_OFF  2080
#define Z_OFF     2112
#define WS_FLOATS (Z_OFF + N_NODES * NTPL)
#define WS_BYTES  ((size_t)WS_FLOATS * 4)

__global__ void ltfwg_prep(const float* __restrict__ tmpl,   // [16][8][8]
                           const float* __restrict__ tfeat,  // [16][8][128]
                           float* __restrict__ ws) {
    const int t   = blockIdx.x;    // 16 blocks
    const int tid = threadIdx.x;   // 128 threads

    float s = 0.f, ssq = 0.f;
    #pragma unroll
    for (int m = 0; m < MTPL; ++m) {
        float v = tfeat[t * (MTPL * NFEAT) + m * NFEAT + tid];
        s += v;
        ssq += v * v;
    }
    ws[TMEAN_OFF + t * NFEAT + tid] = s * 0.125f;

    __shared__ float red[128];
    red[tid] = ssq;
    __syncthreads();
    for (int o = 64; o > 0; o >>= 1) {
        if (tid < o) red[tid] += red[tid + o];
        __syncthreads();
    }
    if (tid == 0) ws[TSQ_OFF + t] = red[0] * 0.125f;

    if (tid < 64) {
        float v = tmpl[t * 64 + tid];
        float sv = v, sv2 = v * v;
        #pragma unroll
        for (int off = 32; off >= 1; off >>= 1) {
            sv  += __shfl_xor(sv, off);
            sv2 += __shfl_xor(sv2, off);
        }
        if (tid == 0) {
            ws[MCT_OFF + t]  = sv  * (1.f / 64.f);
            ws[MCT2_OFF + t] = sv2 * (1.f / 64.f);
        }
    }
}

// Pass 1: thread-per-row GEMV. tmean operands are wave-uniform -> scalar loads.
// No shuffles, no LDS. Writes z[n][16].
__global__ __launch_bounds__(256, 8)
void ltfwg_pass1(const float* __restrict__ x, float* __restrict__ ws) {
    const int n = blockIdx.x * blockDim.x + threadIdx.x;
    if (n >= N_NODES) return;
    const float* tm = ws + TMEAN_OFF;

    float acc[NTPL];
    #pragma unroll
    for (int t = 0; t < NTPL; ++t) acc[t] = 0.f;
    float s2 = 0.f;

    const float4* x4 = (const float4*)x + n * (NFEAT / 4);
    #pragma unroll 4
    for (int j = 0; j < NFEAT / 4; ++j) {
        float4 xv = x4[j];
        s2 += xv.x * xv.x + xv.y * xv.y + xv.z * xv.z + xv.w * xv.w;
        #pragma unroll
        for (int t = 0; t < NTPL; ++t) {
            const float* tr = tm + t * NFEAT + j * 4;   // uniform -> s_load
            acc[t] += xv.x * tr[0] + xv.y * tr[1] + xv.z * tr[2] + xv.w * tr[3];
        }
    }

    float4* z4 = (float4*)(ws + Z_OFF) + n * 4;
    const float h = 0.5f * s2;
    #pragma unroll
    for (int c = 0; c < 4; ++c) {
        float4 zz;
        zz.x = h - acc[4 * c + 0];
        zz.y = h - acc[4 * c + 1];
        zz.z = h - acc[4 * c + 2];
        zz.w = h - acc[4 * c + 3];
        z4[c] = zz;
    }
}

// Pass 2: one wave per node. Feature: lane (a=lane&15, c=lane>>4) gathers
// float4 of z[nbr_a]; 4-step butterfly sums over a. Structure: lane
// (a'=lane>>2, chunk=lane&3) loads int4 of dst[nbr_a'], compares vs all 16
// broadcast neighbor ids (readlane - scalar), quad-OR + popc + 4-step sum.
__global__ __launch_bounds__(256, 8)
void ltfwg_pass2(const int* __restrict__ dst, const float* __restrict__ ws,
                 float* __restrict__ out) {
    const int lane   = threadIdx.x & 63;
    const int wave   = (blockIdx.x * blockDim.x + threadIdx.x) >> 6;
    const int nwaves = (gridDim.x * blockDim.x) >> 6;

    const int tl = ((lane >> 4) << 2) + (lane & 3);          // template id this lane may write
    const float A  = 0.5f * (ws[TSQ_OFF + tl] + ws[MCT2_OFF + tl]);
    const float Bc = 0.5f - ws[MCT_OFF + tl];
    const bool writer = (lane & 15) < 4;
    const float4* z4 = (const float4*)(ws + Z_OFF);

    for (int n = wave; n < N_NODES; n += nwaves) {
        const int nbr = dst[n * KDEG + (lane & 15)];         // a = lane&15

        // ---- feature gather: 16 rows x 64B, 1 line each
        float4 v = z4[nbr * 4 + (lane >> 4)];

        // ---- structure
        int nida = __shfl(nbr, lane >> 2);                   // a' = lane>>2
        int4 cv = ((const int4*)(dst + nida * KDEG))[lane & 3];
        uint32_t m = 0;
        #pragma unroll
        for (int b = 0; b < KDEG; ++b) {
            int vb = __builtin_amdgcn_readlane(nbr, b);      // scalar broadcast
            uint32_t hit = (uint32_t)((cv.x == vb) | (cv.y == vb) |
                                      (cv.z == vb) | (cv.w == vb));
            m |= hit << b;
        }
        m |= (uint32_t)__shfl_xor((int)m, 1);                // OR across quad chunks
        m |= (uint32_t)__shfl_xor((int)m, 2);
        int cm = __popc(m);                                  // rowcount(a'), quad-uniform
        cm += __shfl_xor(cm, 4);
        cm += __shfl_xor(cm, 8);
        cm += __shfl_xor(cm, 16);
        cm += __shfl_xor(cm, 32);                            // total count over 256 pairs

        // ---- z reduction across a (within each 16-lane group)
        float v0 = v.x, v1 = v.y, v2 = v.z, v3 = v.w;
        #pragma unroll
        for (int off = 1; off <= 8; off <<= 1) {
            v0 += __shfl_xor(v0, off);
            v1 += __shfl_xor(v1, off);
            v2 += __shfl_xor(v2, off);
            v3 += __shfl_xor(v3, off);
        }

        if (writer) {
            int j = lane & 3;
            float dsel = (j == 0) ? v0 : (j == 1) ? v1 : (j == 2) ? v2 : v3;
            float val = 0.0625f * dsel + A + (float)cm * (1.f / 256.f) * Bc;
            out[n * NTPL + tl] = val;                        // 16 lanes, one 64B line
        }
    }
}

// Fallback (proven R2 kernel) if ws is too small for the z table.
__global__ __launch_bounds__(256, 4)
void ltfwg_fallback(const float* __restrict__ x, const int* __restrict__ dst,
                    const float* __restrict__ ws, float* __restrict__ out) {
    const int lane   = threadIdx.x & 63;
    const int wave   = (blockIdx.x * blockDim.x + threadIdx.x) >> 6;
    const int nwaves = (gridDim.x * blockDim.x) >> 6;

    float tm0[NTPL], tm1[NTPL];
    #pragma unroll
    for (int t = 0; t < NTPL; ++t) {
        float2 tv = ((const float2*)(ws + t * NFEAT))[lane];
        tm0[t] = tv.x;
        tm1[t] = tv.y;
    }
    const int tl = lane & 15;
    const float A  = 0.5f * (ws[TSQ_OFF + tl] + ws[MCT2_OFF + tl]);
    const float Bc = 0.5f - ws[MCT_OFF + tl];

    for (int n = wave; n < N_NODES; n += nwaves) {
        const int nbr = dst[n * KDEG + (lane & 15)];
        float fs0 = 0.f, fs1 = 0.f, sqa = 0.f;
        #pragma unroll
        for (int a = 0; a < KDEG; ++a) {
            int nid = __shfl(nbr, a);
            float2 fv = ((const float2*)x)[nid * (NFEAT / 2) + lane];
            fs0 += fv.x; fs1 += fv.y;
            sqa += fv.x * fv.x + fv.y * fv.y;
        }
        float dotp[NTPL];
        #pragma unroll
        for (int t = 0; t < NTPL; ++t) dotp[t] = fs0 * tm0[t] + fs1 * tm1[t];

        int nida = __shfl(nbr, lane >> 2);
        const int4* np = (const int4*)(dst + nida * KDEG) + (lane & 3);
        int4 cv = *np;
        uint32_t m = 0;
        #pragma unroll
        for (int b = 0; b < KDEG; ++b) {
            int vb = __shfl(nbr, b);
            uint32_t hit = (uint32_t)((cv.x == vb) | (cv.y == vb) |
                                      (cv.z == vb) | (cv.w == vb));
            m |= hit << b;
        }
        m |= (uint32_t)__shfl_xor((int)m, 1);
        m |= (uint32_t)__shfl_xor((int)m, 2);
        float cnt = (float)__popc(m);

        #pragma unroll
        for (int off = 32; off >= 1; off >>= 1) {
            sqa += __shfl_xor(sqa, off);
            cnt += __shfl_xor(cnt, off);
            #pragma unroll
            for (int t = 0; t < NTPL; ++t) dotp[t] += __shfl_xor(dotp[t], off);
        }
        float dsel = dotp[0];
        #pragma unroll
        for (int t = 1; t < NTPL; ++t) dsel = (lane == t) ? dotp[t] : dsel;

        if (lane < NTPL) {
            float mC = cnt * (1.0f / 1024.0f);
            out[n * NTPL + lane] = 0.03125f * sqa - 0.0625f * dsel + A + mC * Bc;
        }
    }
}

extern "C" void kernel_launch(void* const* d_in, const int* in_sizes, int n_in,
                              void* d_out, int out_size, void* d_ws, size_t ws_size,
                              hipStream_t stream) {
    const float* x     = (const float*)d_in[0];   // f32 [50000,128]
    const int*   edge  = (const int*)d_in[1];     // int32 [2, 800000]
    const float* tmpl  = (const float*)d_in[2];   // f32 [16,8,8]
    const float* tfeat = (const float*)d_in[3];   // f32 [16,8,128]
    float* ws  = (float*)d_ws;
    float* out = (float*)d_out;

    const int* dst = edge + (N_NODES * KDEG);     // edge_index[1]

    ltfwg_prep<<<NTPL, 128, 0, stream>>>(tmpl, tfeat, ws);
    if (ws_size >= WS_BYTES) {
        ltfwg_pass1<<<(N_NODES + 255) / 256, 256, 0, stream>>>(x, ws);
        ltfwg_pass2<<<2048, 256, 0, stream>>>(dst, ws, out);
    } else {
        ltfwg_fallback<<<1024, 256, 0, stream>>>(x, dst, ws, out);
    }
}